// Round 10
// baseline (89.061 us; speedup 1.0000x reference)
//
#include <hip/hip_runtime.h>
#include <hip/hip_bf16.h>

#define S_LEN 4096
#define DHEAD 64
#define KBLK 64
#define CSZ 8          // k-tiles per chunk (512 kv positions)
#define NS 8           // max chunks per q-tile
#define FM 12.0f       // fixed softmax base (log2 domain); cancels in final divide

typedef __attribute__((ext_vector_type(8))) short bf16x8;
typedef __attribute__((ext_vector_type(4))) float f32x4;

__device__ __forceinline__ unsigned short f2bf(float f) {
    union { float f; unsigned u; } v; v.f = f;
    unsigned r = v.u + 0x7fffu + ((v.u >> 16) & 1u);   // RNE
    return (unsigned short)(r >> 16);
}

__device__ __forceinline__ unsigned pack_bf2(float a, float b) {
    __hip_bfloat162 h = __float22bfloat162_rn(float2{a, b});
    union { __hip_bfloat162 h; unsigned u; } cv; cv.h = h;
    return cv.u;
}

// ---------------------------------------------------------------------------
// Phase 1: per-(b, q-tile(128), chunk) partials. 4 waves x 2 q-sets of 16 rows.
// Swapped QK^T (S^T in-register), sigma-permuted V, in-register P, l via
// ones-column MFMA. K/V LDS reads shared across both q-sets. Dbuf, 1 barrier.
// ---------------------------------------------------------------------------
__global__ __launch_bounds__(256) void attn_part(
        const float* __restrict__ Q, const float* __restrict__ K,
        const float* __restrict__ V, const int* __restrict__ mask,
        float* __restrict__ O_part, float* __restrict__ l_part, int Bn)
{
    __shared__ __align__(16) unsigned short K_lds[2][KBLK * DHEAD];   // [buf][k][d]
    __shared__ __align__(16) unsigned short Vt_lds[2][DHEAD * KBLK];  // [buf][d][sigma(k)]
    __shared__ __align__(16) float mb[2][KBLK];                       // mask bias - FM

    const int blk = blockIdx.x;
    const int c   = blk & (NS - 1);
    const int bq  = 31 - ((blk >> 3) & 31);   // LPT: longest q-tiles first
    const int b   = blk >> 8;
    const int nt  = 2 * bq + 2;               // causal k-tiles for 128-row q-tile
    const int k0  = c * CSZ;
    if (k0 >= nt) return;                     // empty chunk
    const int k1  = (k0 + CSZ < nt) ? (k0 + CSZ) : nt;

    const int tid = threadIdx.x;
    const int lane = tid & 63;
    const int wq = tid >> 6;        // 0..3
    const int l15 = lane & 15;
    const int l4 = lane >> 4;       // 0..3
    const int q0 = bq * 128;

    const float sc = 0.125f * 1.44269504088896340736f;  // 1/sqrt(D) * log2(e)

    // ---- Q fragments: 2 sets, q-row(qs) = q0 + qs*64 + wq*16 + l15 ----
    int qgs[2];
    bf16x8 qf[2][2];
    #pragma unroll
    for (int qs = 0; qs < 2; ++qs) {
        qgs[qs] = q0 + qs * 64 + wq * 16 + l15;
        const float* qp = Q + ((size_t)(b * S_LEN + qgs[qs])) * DHEAD + l4 * 8;
        #pragma unroll
        for (int kk = 0; kk < 2; ++kk) {
            float4 a = *(const float4*)(qp + kk * 32);
            float4 cq = *(const float4*)(qp + kk * 32 + 4);
            bf16x8 f;
            f[0] = (short)f2bf(a.x * sc); f[1] = (short)f2bf(a.y * sc);
            f[2] = (short)f2bf(a.z * sc); f[3] = (short)f2bf(a.w * sc);
            f[4] = (short)f2bf(cq.x * sc); f[5] = (short)f2bf(cq.y * sc);
            f[6] = (short)f2bf(cq.z * sc); f[7] = (short)f2bf(cq.w * sc);
            qf[qs][kk] = f;
        }
    }

    const bf16x8 ones = {(short)0x3F80, (short)0x3F80, (short)0x3F80, (short)0x3F80,
                         (short)0x3F80, (short)0x3F80, (short)0x3F80, (short)0x3F80};

    // staging registers
    float4 kv[4];
    float4 vv[4];
    int    mreg;
    const int rp_  = (tid >> 4) << 1;     // V even row base (+32 for r=1)
    const int d4v_ = (tid & 15) << 2;     // V d quad

    auto LOAD_TILE = [&](int kt) {
        const float* kp = K + ((size_t)(b * S_LEN + kt * KBLK)) * DHEAD;
        #pragma unroll
        for (int r = 0; r < 4; ++r) {
            int qi = tid + 256 * r;
            int kr = qi >> 4, d4 = (qi & 15) << 2;
            kv[r] = *(const float4*)(kp + kr * DHEAD + d4);
        }
        const float* vp = V + ((size_t)(b * S_LEN + kt * KBLK)) * DHEAD;
        #pragma unroll
        for (int r = 0; r < 2; ++r) {
            int row0 = rp_ + r * 32;
            vv[2 * r]     = *(const float4*)(vp + row0 * DHEAD + d4v_);
            vv[2 * r + 1] = *(const float4*)(vp + (row0 + 1) * DHEAD + d4v_);
        }
        mreg = mask[(size_t)b * S_LEN + kt * KBLK + (tid & 63)];
    };

    // V swizzle on the write-varying axis: swz(d) = ((d>>1)&7)<<4.
    // Reads (d = t*16+l15, fixed slot-range) stay conflict-free; writes 4-way.
    auto WRITE_TILE = [&](int buf) {
        #pragma unroll
        for (int r = 0; r < 4; ++r) {
            int qi = tid + 256 * r;
            int kr = qi >> 4, d4 = (qi & 15) << 2;
            float4 v = kv[r];
            uint2 h;
            h.x = pack_bf2(v.x, v.y);
            h.y = pack_bf2(v.z, v.w);
            int byte = (kr * 128 + d4 * 2) ^ ((kr & 7) << 4);
            *(uint2*)((char*)&K_lds[buf][0] + byte) = h;
        }
        #pragma unroll
        for (int r = 0; r < 2; ++r) {
            int row0 = rp_ + r * 32;
            // sigma(row0): ct=row0>>4 -> slot = (ct&1)*32 + l4k*8 + (ct>>1)*4 + i
            int ctv = row0 >> 4;
            int sig = (ctv & 1) * 32 + ((row0 >> 2) & 3) * 8 + ((ctv >> 1) << 2) + (row0 & 3);
            float4 a = vv[2 * r];
            float4 cv = vv[2 * r + 1];
            #pragma unroll
            for (int j = 0; j < 4; ++j) {
                int d = d4v_ + j;
                float aj = (j == 0) ? a.x : (j == 1) ? a.y : (j == 2) ? a.z : a.w;
                float cj = (j == 0) ? cv.x : (j == 1) ? cv.y : (j == 2) ? cv.z : cv.w;
                unsigned pack = pack_bf2(aj, cj);   // slots sig, sig+1
                int byte = (d * 128 + sig * 2) ^ (((d >> 1) & 7) << 4);
                *(unsigned*)((char*)&Vt_lds[buf][0] + byte) = pack;
            }
        }
        if (tid < KBLK)
            mb[buf][tid] = mreg ? -FM : -INFINITY;
    };

    f32x4 acc[2][4];
    #pragma unroll
    for (int qs = 0; qs < 2; ++qs)
        for (int t = 0; t < 4; ++t) acc[qs][t] = (f32x4){0.f, 0.f, 0.f, 0.f};
    f32x4 accl[2] = {(f32x4){0.f, 0.f, 0.f, 0.f}, (f32x4){0.f, 0.f, 0.f, 0.f}};

    LOAD_TILE(k0);
    WRITE_TILE(0);
    __syncthreads();
    int cur = 0;

    for (int kt = k0; kt < k1; ++kt) {
        const bool more = (kt + 1 < k1);
        if (more) LOAD_TILE(kt + 1);        // global loads fly under compute

        // ---- QK^T swapped, kf shared by both q-sets ----
        f32x4 s[2][4];
        __builtin_amdgcn_s_setprio(1);
        #pragma unroll
        for (int ct = 0; ct < 4; ++ct) {
            int row = ct * 16 + l15;
            int byte0 = (row * 128 + (l4 * 8) * 2) ^ ((row & 7) << 4);
            int byte1 = (row * 128 + (l4 * 8 + 32) * 2) ^ ((row & 7) << 4);
            bf16x8 kf0 = *(const bf16x8*)((const char*)&K_lds[cur][0] + byte0);
            bf16x8 kf1 = *(const bf16x8*)((const char*)&K_lds[cur][0] + byte1);
            #pragma unroll
            for (int qs = 0; qs < 2; ++qs) {
                f32x4 z = (f32x4){0.f, 0.f, 0.f, 0.f};
                z = __builtin_amdgcn_mfma_f32_16x16x32_bf16(kf0, qf[qs][0], z, 0, 0, 0);
                z = __builtin_amdgcn_mfma_f32_16x16x32_bf16(kf1, qf[qs][1], z, 0, 0, 0);
                s[qs][ct] = z;
            }
        }
        __builtin_amdgcn_s_setprio(0);

        // ---- bias + causal + exp2, in-register; pack pf per q-set ----
        const bool diag = (kt >= nt - 2);   // 128-row q-tile: last 2 k-tiles
        bf16x8 pf[2][2];
        #pragma unroll
        for (int qs = 0; qs < 2; ++qs) {
            f32x4 p[4];
            #pragma unroll
            for (int ct = 0; ct < 4; ++ct) {
                f32x4 bias4 = *(const f32x4*)&mb[cur][ct * 16 + l4 * 4];
                f32x4 v = s[qs][ct] + bias4;
                if (diag) {
                    int kb = kt * 64 + ct * 16 + l4 * 4;
                    #pragma unroll
                    for (int i = 0; i < 4; ++i)
                        if (kb + i > qgs[qs]) v[i] = -INFINITY;
                }
                f32x4 pe;
                pe[0] = exp2f(v[0]); pe[1] = exp2f(v[1]);
                pe[2] = exp2f(v[2]); pe[3] = exp2f(v[3]);
                p[ct] = pe;
            }
            #pragma unroll
            for (int kk = 0; kk < 2; ++kk) {
                union { unsigned u[4]; bf16x8 v; } pk;
                pk.u[0] = pack_bf2(p[kk][0], p[kk][1]);
                pk.u[1] = pack_bf2(p[kk][2], p[kk][3]);
                pk.u[2] = pack_bf2(p[kk + 2][0], p[kk + 2][1]);
                pk.u[3] = pack_bf2(p[kk + 2][2], p[kk + 2][3]);
                pf[qs][kk] = pk.v;
            }
        }

        // ---- PV + denominator, vf shared by both q-sets ----
        __builtin_amdgcn_s_setprio(1);
        #pragma unroll
        for (int kk = 0; kk < 2; ++kk) {
            accl[0] = __builtin_amdgcn_mfma_f32_16x16x32_bf16(pf[0][kk], ones, accl[0], 0, 0, 0);
            accl[1] = __builtin_amdgcn_mfma_f32_16x16x32_bf16(pf[1][kk], ones, accl[1], 0, 0, 0);
            #pragma unroll
            for (int t = 0; t < 4; ++t) {
                int d = t * 16 + l15;
                int vbyte = (d * 128 + (l4 * 8 + kk * 32) * 2) ^ (((d >> 1) & 7) << 4);
                bf16x8 vf = *(const bf16x8*)((const char*)&Vt_lds[cur][0] + vbyte);
                acc[0][t] = __builtin_amdgcn_mfma_f32_16x16x32_bf16(pf[0][kk], vf, acc[0][t], 0, 0, 0);
                acc[1][t] = __builtin_amdgcn_mfma_f32_16x16x32_bf16(pf[1][kk], vf, acc[1][t], 0, 0, 0);
            }
        }
        __builtin_amdgcn_s_setprio(0);

        if (more) {
            WRITE_TILE(cur ^ 1);
            __syncthreads();                // publish next tile; 1 barrier/step
        }
        cur ^= 1;
    }

    // ---- epilogue: O partials + per-row denominator (from accl, col 0) ----
    #pragma unroll
    for (int qs = 0; qs < 2; ++qs) {
        #pragma unroll
        for (int i = 0; i < 4; ++i) {
            int qr = q0 + qs * 64 + wq * 16 + l4 * 4 + i;
            size_t rb = ((size_t)c * Bn + b) * S_LEN + qr;
            float* op = O_part + rb * 64 + l15;
            #pragma unroll
            for (int t = 0; t < 4; ++t)
                op[t * 16] = acc[qs][t][i];
            if (l15 == 0)
                l_part[rb] = accl[qs][i];
        }
    }
}

// ---------------------------------------------------------------------------
// Phase 2: out = (sum_c O_c) / (sum_c l_c)
// ---------------------------------------------------------------------------
__global__ __launch_bounds__(256) void attn_reduce(
        const float* __restrict__ O_part, const float* __restrict__ l_part,
        float* __restrict__ out, int Bn)
{
    int g = blockIdx.x * 4 + (threadIdx.x >> 6);   // global row
    int d = threadIdx.x & 63;
    int b = g >> 12;                               // S_LEN = 4096
    int q = g & (S_LEN - 1);
    int nc = (q >> 9) + 1;                         // chunks covering k <= q

    float den = 0.f, acc = 0.f;
    for (int cc = 0; cc < nc; ++cc) {
        size_t rb = ((size_t)cc * Bn + b) * S_LEN + q;
        den += l_part[rb];
        acc += O_part[rb * 64 + d];
    }
    out[((size_t)b * S_LEN + q) * 64 + d] = acc / den;
}

// ---------------------------------------------------------------------------
// Fallback: proven single-pass kernel (only if ws_size is insufficient)
// ---------------------------------------------------------------------------
__global__ __launch_bounds__(256) void attn_fwd(
        const float* __restrict__ Q, const float* __restrict__ K,
        const float* __restrict__ V, const int* __restrict__ mask,
        float* __restrict__ out)
{
    __shared__ __align__(16) unsigned short K_lds[KBLK * DHEAD];
    __shared__ __align__(16) unsigned short Vt_lds[DHEAD * KBLK];
    __shared__ __align__(16) unsigned short P_lds[4 * 16 * KBLK];
    __shared__ float mb[KBLK];

    const int tid = threadIdx.x;
    const int lane = tid & 63;
    const int wq = tid >> 6;
    const int l15 = lane & 15;
    const int l4 = lane >> 4;

    const int bq = blockIdx.x & 63;
    const int b  = blockIdx.x >> 6;
    const int q0 = bq * 64;
    const int nt = bq + 1;

    const float sc = 0.125f * 1.44269504088896340736f;

    bf16x8 qf[2];
    {
        const float* qp = Q + ((size_t)(b * S_LEN + q0 + wq * 16 + l15)) * DHEAD + l4 * 8;
        for (int kk = 0; kk < 2; ++kk) {
            float4 a = *(const float4*)(qp + kk * 32);
            float4 c = *(const float4*)(qp + kk * 32 + 4);
            bf16x8 f;
            f[0] = (short)f2bf(a.x * sc); f[1] = (short)f2bf(a.y * sc);
            f[2] = (short)f2bf(a.z * sc); f[3] = (short)f2bf(a.w * sc);
            f[4] = (short)f2bf(c.x * sc); f[5] = (short)f2bf(c.y * sc);
            f[6] = (short)f2bf(c.z * sc); f[7] = (short)f2bf(c.w * sc);
            qf[kk] = f;
        }
    }

    float4 kv[4];
    float4 vv[4];
    int    mreg;
    const int rp_  = (tid >> 4) << 1;
    const int d4v_ = (tid & 15) << 2;

    auto LOAD_TILE = [&](int kt) {
        const float* kp = K + ((size_t)(b * S_LEN + kt * KBLK)) * DHEAD;
        #pragma unroll
        for (int r = 0; r < 4; ++r) {
            int qi = tid + 256 * r;
            int kr = qi >> 4, d4 = (qi & 15) << 2;
            kv[r] = *(const float4*)(kp + kr * DHEAD + d4);
        }
        const float* vp = V + ((size_t)(b * S_LEN + kt * KBLK)) * DHEAD;
        #pragma unroll
        for (int r = 0; r < 2; ++r) {
            int row0 = rp_ + r * 32;
            vv[2 * r]     = *(const float4*)(vp + row0 * DHEAD + d4v_);
            vv[2 * r + 1] = *(const float4*)(vp + (row0 + 1) * DHEAD + d4v_);
        }
        mreg = mask[(size_t)b * S_LEN + kt * KBLK + (tid & 63)];
    };

    auto WRITE_TILE = [&]() {
        #pragma unroll
        for (int r = 0; r < 4; ++r) {
            int qi = tid + 256 * r;
            int kr = qi >> 4, d4 = (qi & 15) << 2;
            float4 v = kv[r];
            uint2 h;
            h.x = pack_bf2(v.x, v.y);
            h.y = pack_bf2(v.z, v.w);
            int byte = (kr * 128 + d4 * 2) ^ ((kr & 7) << 4);
            *(uint2*)((char*)K_lds + byte) = h;
        }
        #pragma unroll
        for (int r = 0; r < 2; ++r) {
            int row0 = rp_ + r * 32;
            float4 a = vv[2 * r];
            float4 c = vv[2 * r + 1];
            #pragma unroll
            for (int j = 0; j < 4; ++j) {
                int d = d4v_ + j;
                float aj = (j == 0) ? a.x : (j == 1) ? a.y : (j == 2) ? a.z : a.w;
                float cj = (j == 0) ? c.x : (j == 1) ? c.y : (j == 2) ? c.z : c.w;
                unsigned pack = pack_bf2(aj, cj);
                int byte = (d * 128 + row0 * 2) ^ ((d & 7) << 4);
                *(unsigned*)((char*)Vt_lds + byte) = pack;
            }
        }
        if (tid < KBLK)
            mb[tid] = mreg ? -FM : -INFINITY;
    };

    f32x4 acc[4];
    for (int t = 0; t < 4; ++t) acc[t] = (f32x4){0.f, 0.f, 0.f, 0.f};
    float l_acc[4] = {0.f, 0.f, 0.f, 0.f};

    LOAD_TILE(0);

    for (int kt = 0; kt < nt; ++kt) {
        __syncthreads();
        WRITE_TILE();
        __syncthreads();
        if (kt + 1 < nt) LOAD_TILE(kt + 1);

        f32x4 s[4];
        for (int ct = 0; ct < 4; ++ct) {
            f32x4 z = (f32x4){0.f, 0.f, 0.f, 0.f};
            for (int kk = 0; kk < 2; ++kk) {
                int row = ct * 16 + l15;
                int byte = (row * 128 + (l4 * 8 + kk * 32) * 2) ^ ((row & 7) << 4);
                bf16x8 kf = *(const bf16x8*)((const char*)K_lds + byte);
                z = __builtin_amdgcn_mfma_f32_16x16x32_bf16(qf[kk], kf, z, 0, 0, 0);
            }
            s[ct] = z;
        }

        const bool diag = (kt == nt - 1);
        for (int ct = 0; ct < 4; ++ct) {
            float bias = mb[ct * 16 + l15];
            int colg = kt * KBLK + ct * 16 + l15;
            for (int i = 0; i < 4; ++i) {
                float v = s[ct][i] + bias;
                if (diag) {
                    int qg2 = q0 + wq * 16 + l4 * 4 + i;
                    if (colg > qg2) v = -INFINITY;
                }
                float p = exp2f(v);
                l_acc[i] += p;
                int row = l4 * 4 + i;
                int col = ct * 16 + l15;
                int byte = (row * 128 + col * 2) ^ ((row & 7) << 4);
                *(unsigned short*)((char*)P_lds + wq * 2048 + byte) = f2bf(p);
            }
        }

        for (int kk = 0; kk < 2; ++kk) {
            int pbyte = (l15 * 128 + (l4 * 8 + kk * 32) * 2) ^ ((l15 & 7) << 4);
            bf16x8 pf = *(const bf16x8*)((const char*)P_lds + wq * 2048 + pbyte);
            for (int t = 0; t < 4; ++t) {
                int d = t * 16 + l15;
                int vbyte = (d * 128 + (l4 * 8 + kk * 32) * 2) ^ ((d & 7) << 4);
                bf16x8 vf = *(const bf16x8*)((const char*)Vt_lds + vbyte);
                acc[t] = __builtin_amdgcn_mfma_f32_16x16x32_bf16(pf, vf, acc[t], 0, 0, 0);
            }
        }
    }

    for (int i = 0; i < 4; ++i) {
        float v = l_acc[i];
        v += __shfl_xor(v, 1);
        v += __shfl_xor(v, 2);
        v += __shfl_xor(v, 4);
        v += __shfl_xor(v, 8);
        l_acc[i] = v;
    }

    for (int i = 0; i < 4; ++i) {
        float inv = 1.0f / l_acc[i];
        int qg2 = q0 + wq * 16 + l4 * 4 + i;
        float* op = out + ((size_t)(b * S_LEN + qg2)) * DHEAD + l15;
        for (int t = 0; t < 4; ++t)
            op[t * 16] = acc[t][i] * inv;
    }
}

extern "C" void kernel_launch(void* const* d_in, const int* in_sizes, int n_in,
                              void* d_out, int out_size, void* d_ws, size_t ws_size,
                              hipStream_t stream) {
    const float* Q = (const float*)d_in[0];
    const float* K = (const float*)d_in[1];
    const float* V = (const float*)d_in[2];
    const int* mask = (const int*)d_in[3];
    float* out = (float*)d_out;
    int Bn = in_sizes[0] / (S_LEN * DHEAD);

    size_t need = (size_t)NS * Bn * S_LEN * (64 + 1) * sizeof(float);
    if (ws_size >= need) {
        float* O_part = (float*)d_ws;
        float* l_part = O_part + (size_t)NS * Bn * S_LEN * 64;
        attn_part<<<dim3(Bn * 32 * NS), dim3(256), 0, stream>>>(
            Q, K, V, mask, O_part, l_part, Bn);
        attn_reduce<<<dim3(Bn * S_LEN / 4), dim3(256), 0, stream>>>(
            O_part, l_part, out, Bn);
    } else {
        attn_fwd<<<dim3(Bn * 64), dim3(256), 0, stream>>>(Q, K, V, mask, out);
    }
}

// Round 11
// 62.509 us; speedup vs baseline: 1.4248x; 1.4248x over previous
//
#include <hip/hip_runtime.h>
#include <hip/hip_bf16.h>

#define S_LEN 4096
#define DHEAD 64
#define KBLK 64
#define CSZ 8          // k-tiles per chunk (512 kv positions)
#define NS 8           // max chunks per q-tile
#define FM 12.0f       // fixed softmax base (log2 domain); cancels in final divide

typedef __attribute__((ext_vector_type(8))) short bf16x8;
typedef __attribute__((ext_vector_type(4))) float f32x4;

__device__ __forceinline__ unsigned short f2bf(float f) {
    union { float f; unsigned u; } v; v.f = f;
    unsigned r = v.u + 0x7fffu + ((v.u >> 16) & 1u);   // RNE
    return (unsigned short)(r >> 16);
}

__device__ __forceinline__ unsigned pack_bf2(float a, float b) {
    __hip_bfloat162 h = __float22bfloat162_rn(float2{a, b});
    union { __hip_bfloat162 h; unsigned u; } cv; cv.h = h;
    return cv.u;
}

// ---------------------------------------------------------------------------
// Phase 1: per-(b, q-tile(64), chunk) partials. r9 compute structure
// (swapped QK^T, in-register P, sigma-permuted V) with SINGLE-buffered K/V
// (16.6 KB LDS) to test LDS-gated co-residency. 2 barriers/step (r6 order).
// ---------------------------------------------------------------------------
__global__ __launch_bounds__(256) void attn_part(
        const float* __restrict__ Q, const float* __restrict__ K,
        const float* __restrict__ V, const int* __restrict__ mask,
        float* __restrict__ O_part, float* __restrict__ l_part, int Bn)
{
    __shared__ __align__(16) unsigned short K_lds[KBLK * DHEAD];    // [k][d]
    __shared__ __align__(16) unsigned short Vt_lds[DHEAD * KBLK];   // [d][sigma(k)]
    __shared__ __align__(16) float mb[KBLK];                        // mask bias - FM

    const int blk = blockIdx.x;
    const int c   = blk & (NS - 1);
    const int bq  = 63 - ((blk >> 3) & 63);   // LPT: longest q-tiles first
    const int b   = blk >> 9;
    const int nt  = bq + 1;
    const int k0  = c * CSZ;
    if (k0 >= nt) return;                     // empty chunk
    const int k1  = (k0 + CSZ < nt) ? (k0 + CSZ) : nt;

    const int tid = threadIdx.x;
    const int lane = tid & 63;
    const int wq = tid >> 6;        // 0..3
    const int l15 = lane & 15;
    const int l4 = lane >> 4;       // 0..3
    const int q0 = bq * 64;
    const int qg = q0 + wq * 16 + l15;        // this lane's q-row (swapped layout)

    const float sc = 0.125f * 1.44269504088896340736f;  // 1/sqrt(D) * log2(e)

    // ---- Q fragments (B-operand): q-row = wq*16+l15, d = l4*8 + kk*32 ----
    bf16x8 qf[2];
    {
        const float* qp = Q + ((size_t)(b * S_LEN + qg)) * DHEAD + l4 * 8;
        for (int kk = 0; kk < 2; ++kk) {
            float4 a = *(const float4*)(qp + kk * 32);
            float4 cq = *(const float4*)(qp + kk * 32 + 4);
            bf16x8 f;
            f[0] = (short)f2bf(a.x * sc); f[1] = (short)f2bf(a.y * sc);
            f[2] = (short)f2bf(a.z * sc); f[3] = (short)f2bf(a.w * sc);
            f[4] = (short)f2bf(cq.x * sc); f[5] = (short)f2bf(cq.y * sc);
            f[6] = (short)f2bf(cq.z * sc); f[7] = (short)f2bf(cq.w * sc);
            qf[kk] = f;
        }
    }

    // staging registers
    float4 kv[4];
    float4 vv[4];
    int    mreg;
    const int rp_  = (tid >> 4) << 1;     // V even row base (+32 for r=1)
    const int d4v_ = (tid & 15) << 2;     // V d quad

    auto LOAD_TILE = [&](int kt) {
        const float* kp = K + ((size_t)(b * S_LEN + kt * KBLK)) * DHEAD;
        #pragma unroll
        for (int r = 0; r < 4; ++r) {
            int qi = tid + 256 * r;
            int kr = qi >> 4, d4 = (qi & 15) << 2;
            kv[r] = *(const float4*)(kp + kr * DHEAD + d4);
        }
        const float* vp = V + ((size_t)(b * S_LEN + kt * KBLK)) * DHEAD;
        #pragma unroll
        for (int r = 0; r < 2; ++r) {
            int row0 = rp_ + r * 32;
            vv[2 * r]     = *(const float4*)(vp + row0 * DHEAD + d4v_);
            vv[2 * r + 1] = *(const float4*)(vp + (row0 + 1) * DHEAD + d4v_);
        }
        mreg = mask[(size_t)b * S_LEN + kt * KBLK + (tid & 63)];
    };

    // sigma(k) permutation for V slots; V swizzle on write-varying axis
    // ((d>>1)&7)<<4 — validated in r10 (conflicts 3.7M -> 811K).
    auto WRITE_TILE = [&]() {
        #pragma unroll
        for (int r = 0; r < 4; ++r) {
            int qi = tid + 256 * r;
            int kr = qi >> 4, d4 = (qi & 15) << 2;
            float4 v = kv[r];
            uint2 h;
            h.x = pack_bf2(v.x, v.y);
            h.y = pack_bf2(v.z, v.w);
            int byte = (kr * 128 + d4 * 2) ^ ((kr & 7) << 4);
            *(uint2*)((char*)K_lds + byte) = h;
        }
        #pragma unroll
        for (int r = 0; r < 2; ++r) {
            int row0 = rp_ + r * 32;
            int ctv = row0 >> 4;
            int sig = (ctv & 1) * 32 + ((row0 >> 2) & 3) * 8 + ((ctv >> 1) << 2) + (row0 & 3);
            float4 a = vv[2 * r];
            float4 cv = vv[2 * r + 1];
            #pragma unroll
            for (int j = 0; j < 4; ++j) {
                int d = d4v_ + j;
                float aj = (j == 0) ? a.x : (j == 1) ? a.y : (j == 2) ? a.z : a.w;
                float cj = (j == 0) ? cv.x : (j == 1) ? cv.y : (j == 2) ? cv.z : cv.w;
                unsigned pack = pack_bf2(aj, cj);   // slots sig, sig+1
                int byte = (d * 128 + sig * 2) ^ (((d >> 1) & 7) << 4);
                *(unsigned*)((char*)Vt_lds + byte) = pack;
            }
        }
        if (tid < KBLK)
            mb[tid] = mreg ? -FM : -INFINITY;
    };

    f32x4 acc[4];
    for (int t = 0; t < 4; ++t) acc[t] = (f32x4){0.f, 0.f, 0.f, 0.f};
    f32x4 lacc = (f32x4){0.f, 0.f, 0.f, 0.f};

    LOAD_TILE(k0);

    for (int kt = k0; kt < k1; ++kt) {
        __syncthreads();                    // all waves done reading LDS
        WRITE_TILE();                       // prefetched regs -> LDS
        __syncthreads();                    // publish
        if (kt + 1 < k1) LOAD_TILE(kt + 1); // next tile flies under compute

        // ---- QK^T swapped: s[ct][i] = score(q=qg, k = kt*64 + ct*16 + l4*4 + i)
        f32x4 s[4];
        __builtin_amdgcn_s_setprio(1);
        #pragma unroll
        for (int ct = 0; ct < 4; ++ct) {
            f32x4 z = (f32x4){0.f, 0.f, 0.f, 0.f};
            #pragma unroll
            for (int kk = 0; kk < 2; ++kk) {
                int row = ct * 16 + l15;
                int byte = (row * 128 + (l4 * 8 + kk * 32) * 2) ^ ((row & 7) << 4);
                bf16x8 kf = *(const bf16x8*)((const char*)K_lds + byte);
                z = __builtin_amdgcn_mfma_f32_16x16x32_bf16(kf, qf[kk], z, 0, 0, 0);
            }
            s[ct] = z;
        }
        __builtin_amdgcn_s_setprio(0);

        // ---- bias + causal + exp2, all in-register ----
        const bool diag = (kt == nt - 1);
        f32x4 p[4];
        #pragma unroll
        for (int ct = 0; ct < 4; ++ct) {
            f32x4 bias4 = *(const f32x4*)&mb[ct * 16 + l4 * 4];
            f32x4 v = s[ct] + bias4;
            if (diag) {
                int kb = kt * 64 + ct * 16 + l4 * 4;
                #pragma unroll
                for (int i = 0; i < 4; ++i)
                    if (kb + i > qg) v[i] = -INFINITY;
            }
            f32x4 pe;
            pe[0] = exp2f(v[0]); pe[1] = exp2f(v[1]);
            pe[2] = exp2f(v[2]); pe[3] = exp2f(v[3]);
            p[ct] = pe;
            lacc += pe;
        }

        // ---- pack P fragments in-register (matches sigma-permuted V) ----
        bf16x8 pf[2];
        #pragma unroll
        for (int kk = 0; kk < 2; ++kk) {
            union { unsigned u[4]; bf16x8 v; } pk;
            pk.u[0] = pack_bf2(p[kk][0], p[kk][1]);
            pk.u[1] = pack_bf2(p[kk][2], p[kk][3]);
            pk.u[2] = pack_bf2(p[kk + 2][0], p[kk + 2][1]);
            pk.u[3] = pack_bf2(p[kk + 2][2], p[kk + 2][3]);
            pf[kk] = pk.v;
        }

        // ---- PV: acc[t] += pf * Vt ----
        __builtin_amdgcn_s_setprio(1);
        #pragma unroll
        for (int kk = 0; kk < 2; ++kk) {
            #pragma unroll
            for (int t = 0; t < 4; ++t) {
                int d = t * 16 + l15;
                int vbyte = (d * 128 + (l4 * 8 + kk * 32) * 2) ^ (((d >> 1) & 7) << 4);
                bf16x8 vf = *(const bf16x8*)((const char*)Vt_lds + vbyte);
                acc[t] = __builtin_amdgcn_mfma_f32_16x16x32_bf16(pf[kk], vf, acc[t], 0, 0, 0);
            }
        }
        __builtin_amdgcn_s_setprio(0);
    }

    // ---- row denominator: lane owns q=qg slice; reduce across l4 group ----
    float la = lacc[0] + lacc[1] + lacc[2] + lacc[3];
    la += __shfl_xor(la, 16);
    la += __shfl_xor(la, 32);

    for (int i = 0; i < 4; ++i) {
        int qr = q0 + wq * 16 + l4 * 4 + i;
        size_t rb = ((size_t)c * Bn + b) * S_LEN + qr;
        float* op = O_part + rb * 64 + l15;
        #pragma unroll
        for (int t = 0; t < 4; ++t)
            op[t * 16] = acc[t][i];
    }
    if (l4 == 0) {
        size_t rb = ((size_t)c * Bn + b) * S_LEN + qg;
        l_part[rb] = la;
    }
}

// ---------------------------------------------------------------------------
// Phase 2: out = (sum_c O_c) / (sum_c l_c)
// ---------------------------------------------------------------------------
__global__ __launch_bounds__(256) void attn_reduce(
        const float* __restrict__ O_part, const float* __restrict__ l_part,
        float* __restrict__ out, int Bn)
{
    int g = blockIdx.x * 4 + (threadIdx.x >> 6);   // global row
    int d = threadIdx.x & 63;
    int b = g >> 12;                               // S_LEN = 4096
    int q = g & (S_LEN - 1);
    int nc = (q >> 9) + 1;                         // chunks covering k <= q

    float den = 0.f, acc = 0.f;
    for (int cc = 0; cc < nc; ++cc) {
        size_t rb = ((size_t)cc * Bn + b) * S_LEN + q;
        den += l_part[rb];
        acc += O_part[rb * 64 + d];
    }
    out[((size_t)b * S_LEN + q) * 64 + d] = acc / den;
}

// ---------------------------------------------------------------------------
// Fallback: proven single-pass kernel (only if ws_size is insufficient)
// ---------------------------------------------------------------------------
__global__ __launch_bounds__(256) void attn_fwd(
        const float* __restrict__ Q, const float* __restrict__ K,
        const float* __restrict__ V, const int* __restrict__ mask,
        float* __restrict__ out)
{
    __shared__ __align__(16) unsigned short K_lds[KBLK * DHEAD];
    __shared__ __align__(16) unsigned short Vt_lds[DHEAD * KBLK];
    __shared__ __align__(16) unsigned short P_lds[4 * 16 * KBLK];
    __shared__ float mb[KBLK];

    const int tid = threadIdx.x;
    const int lane = tid & 63;
    const int wq = tid >> 6;
    const int l15 = lane & 15;
    const int l4 = lane >> 4;

    const int bq = blockIdx.x & 63;
    const int b  = blockIdx.x >> 6;
    const int q0 = bq * 64;
    const int nt = bq + 1;

    const float sc = 0.125f * 1.44269504088896340736f;

    bf16x8 qf[2];
    {
        const float* qp = Q + ((size_t)(b * S_LEN + q0 + wq * 16 + l15)) * DHEAD + l4 * 8;
        for (int kk = 0; kk < 2; ++kk) {
            float4 a = *(const float4*)(qp + kk * 32);
            float4 c = *(const float4*)(qp + kk * 32 + 4);
            bf16x8 f;
            f[0] = (short)f2bf(a.x * sc); f[1] = (short)f2bf(a.y * sc);
            f[2] = (short)f2bf(a.z * sc); f[3] = (short)f2bf(a.w * sc);
            f[4] = (short)f2bf(c.x * sc); f[5] = (short)f2bf(c.y * sc);
            f[6] = (short)f2bf(c.z * sc); f[7] = (short)f2bf(c.w * sc);
            qf[kk] = f;
        }
    }

    float4 kv[4];
    float4 vv[4];
    int    mreg;
    const int rp_  = (tid >> 4) << 1;
    const int d4v_ = (tid & 15) << 2;

    auto LOAD_TILE = [&](int kt) {
        const float* kp = K + ((size_t)(b * S_LEN + kt * KBLK)) * DHEAD;
        #pragma unroll
        for (int r = 0; r < 4; ++r) {
            int qi = tid + 256 * r;
            int kr = qi >> 4, d4 = (qi & 15) << 2;
            kv[r] = *(const float4*)(kp + kr * DHEAD + d4);
        }
        const float* vp = V + ((size_t)(b * S_LEN + kt * KBLK)) * DHEAD;
        #pragma unroll
        for (int r = 0; r < 2; ++r) {
            int row0 = rp_ + r * 32;
            vv[2 * r]     = *(const float4*)(vp + row0 * DHEAD + d4v_);
            vv[2 * r + 1] = *(const float4*)(vp + (row0 + 1) * DHEAD + d4v_);
        }
        mreg = mask[(size_t)b * S_LEN + kt * KBLK + (tid & 63)];
    };

    auto WRITE_TILE = [&]() {
        #pragma unroll
        for (int r = 0; r < 4; ++r) {
            int qi = tid + 256 * r;
            int kr = qi >> 4, d4 = (qi & 15) << 2;
            float4 v = kv[r];
            uint2 h;
            h.x = pack_bf2(v.x, v.y);
            h.y = pack_bf2(v.z, v.w);
            int byte = (kr * 128 + d4 * 2) ^ ((kr & 7) << 4);
            *(uint2*)((char*)K_lds + byte) = h;
        }
        #pragma unroll
        for (int r = 0; r < 2; ++r) {
            int row0 = rp_ + r * 32;
            float4 a = vv[2 * r];
            float4 c = vv[2 * r + 1];
            #pragma unroll
            for (int j = 0; j < 4; ++j) {
                int d = d4v_ + j;
                float aj = (j == 0) ? a.x : (j == 1) ? a.y : (j == 2) ? a.z : a.w;
                float cj = (j == 0) ? c.x : (j == 1) ? c.y : (j == 2) ? c.z : c.w;
                unsigned pack = pack_bf2(aj, cj);
                int byte = (d * 128 + row0 * 2) ^ ((d & 7) << 4);
                *(unsigned*)((char*)Vt_lds + byte) = pack;
            }
        }
        if (tid < KBLK)
            mb[tid] = mreg ? -FM : -INFINITY;
    };

    f32x4 acc[4];
    for (int t = 0; t < 4; ++t) acc[t] = (f32x4){0.f, 0.f, 0.f, 0.f};
    float l_acc[4] = {0.f, 0.f, 0.f, 0.f};

    LOAD_TILE(0);

    for (int kt = 0; kt < nt; ++kt) {
        __syncthreads();
        WRITE_TILE();
        __syncthreads();
        if (kt + 1 < nt) LOAD_TILE(kt + 1);

        f32x4 s[4];
        for (int ct = 0; ct < 4; ++ct) {
            f32x4 z = (f32x4){0.f, 0.f, 0.f, 0.f};
            for (int kk = 0; kk < 2; ++kk) {
                int row = ct * 16 + l15;
                int byte = (row * 128 + (l4 * 8 + kk * 32) * 2) ^ ((row & 7) << 4);
                bf16x8 kf = *(const bf16x8*)((const char*)K_lds + byte);
                z = __builtin_amdgcn_mfma_f32_16x16x32_bf16(qf[kk], kf, z, 0, 0, 0);
            }
            s[ct] = z;
        }

        const bool diag = (kt == nt - 1);
        for (int ct = 0; ct < 4; ++ct) {
            float bias = mb[ct * 16 + l15];
            int colg = kt * KBLK + ct * 16 + l15;
            for (int i = 0; i < 4; ++i) {
                float v = s[ct][i] + bias;
                if (diag) {
                    int qg2 = q0 + wq * 16 + l4 * 4 + i;
                    if (colg > qg2) v = -INFINITY;
                }
                float p = exp2f(v);
                l_acc[i] += p;
                int row = l4 * 4 + i;
                int col = ct * 16 + l15;
                int byte = (row * 128 + col * 2) ^ ((row & 7) << 4);
                *(unsigned short*)((char*)P_lds + wq * 2048 + byte) = f2bf(p);
            }
        }

        for (int kk = 0; kk < 2; ++kk) {
            int pbyte = (l15 * 128 + (l4 * 8 + kk * 32) * 2) ^ ((l15 & 7) << 4);
            bf16x8 pf = *(const bf16x8*)((const char*)P_lds + wq * 2048 + pbyte);
            for (int t = 0; t < 4; ++t) {
                int d = t * 16 + l15;
                int vbyte = (d * 128 + (l4 * 8 + kk * 32) * 2) ^ ((d & 7) << 4);
                bf16x8 vf = *(const bf16x8*)((const char*)Vt_lds + vbyte);
                acc[t] = __builtin_amdgcn_mfma_f32_16x16x32_bf16(pf, vf, acc[t], 0, 0, 0);
            }
        }
    }

    for (int i = 0; i < 4; ++i) {
        float v = l_acc[i];
        v += __shfl_xor(v, 1);
        v += __shfl_xor(v, 2);
        v += __shfl_xor(v, 4);
        v += __shfl_xor(v, 8);
        l_acc[i] = v;
    }

    for (int i = 0; i < 4; ++i) {
        float inv = 1.0f / l_acc[i];
        int qg2 = q0 + wq * 16 + l4 * 4 + i;
        float* op = out + ((size_t)(b * S_LEN + qg2)) * DHEAD + l15;
        for (int t = 0; t < 4; ++t)
            op[t * 16] = acc[t][i] * inv;
    }
}

extern "C" void kernel_launch(void* const* d_in, const int* in_sizes, int n_in,
                              void* d_out, int out_size, void* d_ws, size_t ws_size,
                              hipStream_t stream) {
    const float* Q = (const float*)d_in[0];
    const float* K = (const float*)d_in[1];
    const float* V = (const float*)d_in[2];
    const int* mask = (const int*)d_in[3];
    float* out = (float*)d_out;
    int Bn = in_sizes[0] / (S_LEN * DHEAD);

    size_t need = (size_t)NS * Bn * S_LEN * (64 + 1) * sizeof(float);
    if (ws_size >= need) {
        float* O_part = (float*)d_ws;
        float* l_part = O_part + (size_t)NS * Bn * S_LEN * 64;
        attn_part<<<dim3(Bn * 64 * NS), dim3(256), 0, stream>>>(
            Q, K, V, mask, O_part, l_part, Bn);
        attn_reduce<<<dim3(Bn * S_LEN / 4), dim3(256), 0, stream>>>(
            O_part, l_part, out, Bn);
    } else {
        attn_fwd<<<dim3(Bn * 64), dim3(256), 0, stream>>>(Q, K, V, mask, out);
    }
}

// Round 12
// 56.659 us; speedup vs baseline: 1.5719x; 1.1032x over previous
//
#include <hip/hip_runtime.h>
#include <hip/hip_bf16.h>

#define S_LEN 4096
#define DHEAD 64
#define KBLK 64
#define CSZ 8          // k-tiles per chunk (512 kv positions)
#define NS 8           // max chunks per q-tile
#define FM 12.0f       // fixed softmax base (log2 domain); cancels in final divide

typedef __attribute__((ext_vector_type(8))) short bf16x8;
typedef __attribute__((ext_vector_type(8))) unsigned short u16x8;
typedef __attribute__((ext_vector_type(4))) float f32x4;

__device__ __forceinline__ unsigned short f2bf(float f) {
    union { float f; unsigned u; } v; v.f = f;
    unsigned r = v.u + 0x7fffu + ((v.u >> 16) & 1u);   // RNE
    return (unsigned short)(r >> 16);
}

__device__ __forceinline__ float bf2f(unsigned short h) {
    union { unsigned u; float f; } v; v.u = ((unsigned)h) << 16; return v.f;
}

__device__ __forceinline__ unsigned pack_bf2(float a, float b) {
    __hip_bfloat162 h = __float22bfloat162_rn(float2{a, b});
    union { __hip_bfloat162 h; unsigned u; } cv; cv.h = h;
    return cv.u;
}

// async global->LDS, 16B per lane; lds ptr is WAVE-UNIFORM base (HW adds lane*16)
__device__ __forceinline__ void gl_lds16(const void* g, void* l) {
    __builtin_amdgcn_global_load_lds(
        (const __attribute__((address_space(1))) void*)g,
        (__attribute__((address_space(3))) void*)l, 16, 0, 0);
}

// ---------------------------------------------------------------------------
// Prepass: build bf16 tile blobs = exact LDS images (swizzle + sigma baked in).
// K image byte: (kr*128 + d*2) ^ ((kr&7)<<4)
// V image byte: (d*128 + sig(k)*2) ^ (((d>>1)&7)<<4),
//   sig(k) = (ct&1)*32 + l4k*8 + (ct>>1)*4 + i  for k = ct*16 + l4k*4 + i
// Thread owns a 16B OUTPUT chunk (XOR flips bit4 only -> 16B chunks map to
// 16B chunks); inverse mapping computed analytically.
// ---------------------------------------------------------------------------
__global__ __launch_bounds__(256) void prep(
        const float* __restrict__ K, const float* __restrict__ V,
        unsigned short* __restrict__ Kb, unsigned short* __restrict__ Vb)
{
    const int tile = blockIdx.x;            // b*64 + kt
    const int b = tile >> 6, kt = tile & 63;
    const float* kp = K + ((size_t)(b * S_LEN + kt * KBLK)) * DHEAD;
    const float* vp = V + ((size_t)(b * S_LEN + kt * KBLK)) * DHEAD;
    unsigned short* kb = Kb + (size_t)tile * 4096;
    unsigned short* vb = Vb + (size_t)tile * 4096;
    const int tid = threadIdx.x;

    #pragma unroll
    for (int r = 0; r < 2; ++r) {
        int ci = r * 256 + tid;
        int base = ci * 16;                  // output byte
        int kr = base >> 7;
        int low = (base & 127) ^ ((kr & 7) << 4);
        int d0 = low >> 1;                   // 8 consecutive d
        u16x8 o;
        #pragma unroll
        for (int j = 0; j < 8; ++j) o[j] = f2bf(kp[kr * DHEAD + d0 + j]);
        *(u16x8*)(kb + ci * 8) = o;
    }
    #pragma unroll
    for (int r = 0; r < 2; ++r) {
        int ci = r * 256 + tid;
        int base = ci * 16;
        int d = base >> 7;
        int low = (base & 127) ^ (((d >> 1) & 7) << 4);
        int slot0 = low >> 1;                // multiple of 8
        u16x8 o;
        #pragma unroll
        for (int j = 0; j < 8; ++j) {
            int slot = slot0 + j;
            int ct = 2 * ((slot >> 2) & 1) + ((slot >> 5) & 1);
            int k = ct * 16 + ((slot >> 3) & 3) * 4 + (slot & 3);
            o[j] = f2bf(vp[k * DHEAD + d]);
        }
        *(u16x8*)(vb + ci * 8) = o;
    }
}

// ---------------------------------------------------------------------------
// Phase 1: r11 compute (swapped QK^T, in-register P, sigma-permuted V) with
// staging via global_load_lds from pre-built blobs. Dbuf, 1 barrier/step.
// O partials stored bf16.
// ---------------------------------------------------------------------------
__global__ __launch_bounds__(256) void attn_part(
        const float* __restrict__ Q, const unsigned short* __restrict__ Kb,
        const unsigned short* __restrict__ Vb, const int* __restrict__ mask,
        unsigned short* __restrict__ O_part, float* __restrict__ l_part, int Bn)
{
    __shared__ __align__(16) unsigned short K_lds[2][4096];
    __shared__ __align__(16) unsigned short V_lds[2][4096];
    __shared__ __align__(16) float mb[2][KBLK];

    const int blk = blockIdx.x;
    const int c   = blk & (NS - 1);
    const int bq  = 63 - ((blk >> 3) & 63);   // LPT
    const int b   = blk >> 9;
    const int nt  = bq + 1;
    const int k0  = c * CSZ;
    if (k0 >= nt) return;
    const int k1  = (k0 + CSZ < nt) ? (k0 + CSZ) : nt;

    const int tid = threadIdx.x;
    const int lane = tid & 63;
    const int wq = tid >> 6;
    const int l15 = lane & 15;
    const int l4 = lane >> 4;
    const int q0 = bq * 64;
    const int qg = q0 + wq * 16 + l15;

    const float sc = 0.125f * 1.44269504088896340736f;

    bf16x8 qf[2];
    {
        const float* qp = Q + ((size_t)(b * S_LEN + qg)) * DHEAD + l4 * 8;
        for (int kk = 0; kk < 2; ++kk) {
            float4 a = *(const float4*)(qp + kk * 32);
            float4 cq = *(const float4*)(qp + kk * 32 + 4);
            bf16x8 f;
            f[0] = (short)f2bf(a.x * sc); f[1] = (short)f2bf(a.y * sc);
            f[2] = (short)f2bf(a.z * sc); f[3] = (short)f2bf(a.w * sc);
            f[4] = (short)f2bf(cq.x * sc); f[5] = (short)f2bf(cq.y * sc);
            f[6] = (short)f2bf(cq.z * sc); f[7] = (short)f2bf(cq.w * sc);
            qf[kk] = f;
        }
    }

    int mreg;
    auto STAGE = [&](int kt, int buf) {
        const unsigned short* kb = Kb + ((size_t)(b * 64 + kt)) * 4096;
        const unsigned short* vb = Vb + ((size_t)(b * 64 + kt)) * 4096;
        #pragma unroll
        for (int r = 0; r < 2; ++r) {
            int ci = r * 256 + tid;
            int ub = (r * 256 + wq * 64) * 16;   // wave-uniform LDS byte base
            gl_lds16(kb + ci * 8, (char*)&K_lds[buf][0] + ub);
            gl_lds16(vb + ci * 8, (char*)&V_lds[buf][0] + ub);
        }
        mreg = mask[(size_t)b * S_LEN + kt * KBLK + lane];
    };

    f32x4 acc[4];
    for (int t = 0; t < 4; ++t) acc[t] = (f32x4){0.f, 0.f, 0.f, 0.f};
    f32x4 lacc = (f32x4){0.f, 0.f, 0.f, 0.f};

    STAGE(k0, 0);
    if (tid < KBLK) mb[0][tid] = mreg ? -FM : -INFINITY;
    __syncthreads();                       // drains gload_lds (vmcnt) + publishes
    int cur = 0;

    for (int kt = k0; kt < k1; ++kt) {
        const bool more = (kt + 1 < k1);
        if (more) STAGE(kt + 1, cur ^ 1);  // DMA flies under compute below

        // ---- QK^T swapped ----
        f32x4 s[4];
        __builtin_amdgcn_s_setprio(1);
        #pragma unroll
        for (int ct = 0; ct < 4; ++ct) {
            f32x4 z = (f32x4){0.f, 0.f, 0.f, 0.f};
            #pragma unroll
            for (int kk = 0; kk < 2; ++kk) {
                int row = ct * 16 + l15;
                int byte = (row * 128 + (l4 * 8 + kk * 32) * 2) ^ ((row & 7) << 4);
                bf16x8 kf = *(const bf16x8*)((const char*)&K_lds[cur][0] + byte);
                z = __builtin_amdgcn_mfma_f32_16x16x32_bf16(kf, qf[kk], z, 0, 0, 0);
            }
            s[ct] = z;
        }
        __builtin_amdgcn_s_setprio(0);

        // ---- bias + causal + exp2 in-register ----
        const bool diag = (kt == nt - 1);
        f32x4 p[4];
        #pragma unroll
        for (int ct = 0; ct < 4; ++ct) {
            f32x4 bias4 = *(const f32x4*)&mb[cur][ct * 16 + l4 * 4];
            f32x4 v = s[ct] + bias4;
            if (diag) {
                int kb_ = kt * 64 + ct * 16 + l4 * 4;
                #pragma unroll
                for (int i = 0; i < 4; ++i)
                    if (kb_ + i > qg) v[i] = -INFINITY;
            }
            f32x4 pe;
            pe[0] = exp2f(v[0]); pe[1] = exp2f(v[1]);
            pe[2] = exp2f(v[2]); pe[3] = exp2f(v[3]);
            p[ct] = pe;
            lacc += pe;
        }

        // ---- pack P fragments (matches sigma-permuted V) ----
        bf16x8 pf[2];
        #pragma unroll
        for (int kk = 0; kk < 2; ++kk) {
            union { unsigned u[4]; bf16x8 v; } pk;
            pk.u[0] = pack_bf2(p[kk][0], p[kk][1]);
            pk.u[1] = pack_bf2(p[kk][2], p[kk][3]);
            pk.u[2] = pack_bf2(p[kk + 2][0], p[kk + 2][1]);
            pk.u[3] = pack_bf2(p[kk + 2][2], p[kk + 2][3]);
            pf[kk] = pk.v;
        }

        // ---- PV ----
        __builtin_amdgcn_s_setprio(1);
        #pragma unroll
        for (int kk = 0; kk < 2; ++kk) {
            #pragma unroll
            for (int t = 0; t < 4; ++t) {
                int d = t * 16 + l15;
                int vbyte = (d * 128 + (l4 * 8 + kk * 32) * 2) ^ (((d >> 1) & 7) << 4);
                bf16x8 vf = *(const bf16x8*)((const char*)&V_lds[cur][0] + vbyte);
                acc[t] = __builtin_amdgcn_mfma_f32_16x16x32_bf16(pf[kk], vf, acc[t], 0, 0, 0);
            }
        }
        __builtin_amdgcn_s_setprio(0);

        if (more && tid < KBLK) mb[cur ^ 1][tid] = mreg ? -FM : -INFINITY;
        __syncthreads();                   // drains next-tile DMA + publishes
        cur ^= 1;
    }

    // ---- row denominator ----
    float la = lacc[0] + lacc[1] + lacc[2] + lacc[3];
    la += __shfl_xor(la, 16);
    la += __shfl_xor(la, 32);

    for (int i = 0; i < 4; ++i) {
        int qr = q0 + wq * 16 + l4 * 4 + i;
        size_t rb = ((size_t)c * Bn + b) * S_LEN + qr;
        unsigned short* op = O_part + rb * 64 + l15;
        #pragma unroll
        for (int t = 0; t < 4; ++t)
            op[t * 16] = f2bf(acc[t][i]);
    }
    if (l4 == 0) {
        size_t rb = ((size_t)c * Bn + b) * S_LEN + qg;
        l_part[rb] = la;
    }
}

// ---------------------------------------------------------------------------
// Phase 2: out = (sum_c O_c) / (sum_c l_c)   (bf16 partials)
// ---------------------------------------------------------------------------
__global__ __launch_bounds__(256) void attn_reduce(
        const unsigned short* __restrict__ O_part, const float* __restrict__ l_part,
        float* __restrict__ out, int Bn)
{
    int g = blockIdx.x * 4 + (threadIdx.x >> 6);
    int d = threadIdx.x & 63;
    int b = g >> 12;
    int q = g & (S_LEN - 1);
    int nc = (q >> 9) + 1;

    float den = 0.f, acc = 0.f;
    for (int cc = 0; cc < nc; ++cc) {
        size_t rb = ((size_t)cc * Bn + b) * S_LEN + q;
        den += l_part[rb];
        acc += bf2f(O_part[rb * 64 + d]);
    }
    out[((size_t)b * S_LEN + q) * 64 + d] = acc / den;
}

// ---------------------------------------------------------------------------
// Fallback: proven single-pass kernel (only if ws_size is insufficient)
// ---------------------------------------------------------------------------
__global__ __launch_bounds__(256) void attn_fwd(
        const float* __restrict__ Q, const float* __restrict__ K,
        const float* __restrict__ V, const int* __restrict__ mask,
        float* __restrict__ out)
{
    __shared__ __align__(16) unsigned short K_lds[KBLK * DHEAD];
    __shared__ __align__(16) unsigned short Vt_lds[DHEAD * KBLK];
    __shared__ __align__(16) unsigned short P_lds[4 * 16 * KBLK];
    __shared__ float mb[KBLK];

    const int tid = threadIdx.x;
    const int lane = tid & 63;
    const int wq = tid >> 6;
    const int l15 = lane & 15;
    const int l4 = lane >> 4;

    const int bq = blockIdx.x & 63;
    const int b  = blockIdx.x >> 6;
    const int q0 = bq * 64;
    const int nt = bq + 1;

    const float sc = 0.125f * 1.44269504088896340736f;

    bf16x8 qf[2];
    {
        const float* qp = Q + ((size_t)(b * S_LEN + q0 + wq * 16 + l15)) * DHEAD + l4 * 8;
        for (int kk = 0; kk < 2; ++kk) {
            float4 a = *(const float4*)(qp + kk * 32);
            float4 c = *(const float4*)(qp + kk * 32 + 4);
            bf16x8 f;
            f[0] = (short)f2bf(a.x * sc); f[1] = (short)f2bf(a.y * sc);
            f[2] = (short)f2bf(a.z * sc); f[3] = (short)f2bf(a.w * sc);
            f[4] = (short)f2bf(c.x * sc); f[5] = (short)f2bf(c.y * sc);
            f[6] = (short)f2bf(c.z * sc); f[7] = (short)f2bf(c.w * sc);
            qf[kk] = f;
        }
    }

    float4 kv[4];
    float4 vv[4];
    int    mreg;
    const int rp_  = (tid >> 4) << 1;
    const int d4v_ = (tid & 15) << 2;

    auto LOAD_TILE = [&](int kt) {
        const float* kp = K + ((size_t)(b * S_LEN + kt * KBLK)) * DHEAD;
        #pragma unroll
        for (int r = 0; r < 4; ++r) {
            int qi = tid + 256 * r;
            int kr = qi >> 4, d4 = (qi & 15) << 2;
            kv[r] = *(const float4*)(kp + kr * DHEAD + d4);
        }
        const float* vp = V + ((size_t)(b * S_LEN + kt * KBLK)) * DHEAD;
        #pragma unroll
        for (int r = 0; r < 2; ++r) {
            int row0 = rp_ + r * 32;
            vv[2 * r]     = *(const float4*)(vp + row0 * DHEAD + d4v_);
            vv[2 * r + 1] = *(const float4*)(vp + (row0 + 1) * DHEAD + d4v_);
        }
        mreg = mask[(size_t)b * S_LEN + kt * KBLK + (tid & 63)];
    };

    auto WRITE_TILE = [&]() {
        #pragma unroll
        for (int r = 0; r < 4; ++r) {
            int qi = tid + 256 * r;
            int kr = qi >> 4, d4 = (qi & 15) << 2;
            float4 v = kv[r];
            uint2 h;
            h.x = pack_bf2(v.x, v.y);
            h.y = pack_bf2(v.z, v.w);
            int byte = (kr * 128 + d4 * 2) ^ ((kr & 7) << 4);
            *(uint2*)((char*)K_lds + byte) = h;
        }
        #pragma unroll
        for (int r = 0; r < 2; ++r) {
            int row0 = rp_ + r * 32;
            float4 a = vv[2 * r];
            float4 c = vv[2 * r + 1];
            #pragma unroll
            for (int j = 0; j < 4; ++j) {
                int d = d4v_ + j;
                float aj = (j == 0) ? a.x : (j == 1) ? a.y : (j == 2) ? a.z : a.w;
                float cj = (j == 0) ? c.x : (j == 1) ? c.y : (j == 2) ? c.z : c.w;
                unsigned pack = pack_bf2(aj, cj);
                int byte = (d * 128 + row0 * 2) ^ ((d & 7) << 4);
                *(unsigned*)((char*)Vt_lds + byte) = pack;
            }
        }
        if (tid < KBLK)
            mb[tid] = mreg ? -FM : -INFINITY;
    };

    f32x4 acc[4];
    for (int t = 0; t < 4; ++t) acc[t] = (f32x4){0.f, 0.f, 0.f, 0.f};
    float l_acc[4] = {0.f, 0.f, 0.f, 0.f};

    LOAD_TILE(0);

    for (int kt = 0; kt < nt; ++kt) {
        __syncthreads();
        WRITE_TILE();
        __syncthreads();
        if (kt + 1 < nt) LOAD_TILE(kt + 1);

        f32x4 s[4];
        for (int ct = 0; ct < 4; ++ct) {
            f32x4 z = (f32x4){0.f, 0.f, 0.f, 0.f};
            for (int kk = 0; kk < 2; ++kk) {
                int row = ct * 16 + l15;
                int byte = (row * 128 + (l4 * 8 + kk * 32) * 2) ^ ((row & 7) << 4);
                bf16x8 kf = *(const bf16x8*)((const char*)K_lds + byte);
                z = __builtin_amdgcn_mfma_f32_16x16x32_bf16(qf[kk], kf, z, 0, 0, 0);
            }
            s[ct] = z;
        }

        const bool diag = (kt == nt - 1);
        for (int ct = 0; ct < 4; ++ct) {
            float bias = mb[ct * 16 + l15];
            int colg = kt * KBLK + ct * 16 + l15;
            for (int i = 0; i < 4; ++i) {
                float v = s[ct][i] + bias;
                if (diag) {
                    int qg2 = q0 + wq * 16 + l4 * 4 + i;
                    if (colg > qg2) v = -INFINITY;
                }
                float p = exp2f(v);
                l_acc[i] += p;
                int row = l4 * 4 + i;
                int col = ct * 16 + l15;
                int byte = (row * 128 + col * 2) ^ ((row & 7) << 4);
                *(unsigned short*)((char*)P_lds + wq * 2048 + byte) = f2bf(p);
            }
        }

        for (int kk = 0; kk < 2; ++kk) {
            int pbyte = (l15 * 128 + (l4 * 8 + kk * 32) * 2) ^ ((l15 & 7) << 4);
            bf16x8 pf = *(const bf16x8*)((const char*)P_lds + wq * 2048 + pbyte);
            for (int t = 0; t < 4; ++t) {
                int d = t * 16 + l15;
                int vbyte = (d * 128 + (l4 * 8 + kk * 32) * 2) ^ ((d & 7) << 4);
                bf16x8 vf = *(const bf16x8*)((const char*)Vt_lds + vbyte);
                acc[t] = __builtin_amdgcn_mfma_f32_16x16x32_bf16(pf, vf, acc[t], 0, 0, 0);
            }
        }
    }

    for (int i = 0; i < 4; ++i) {
        float v = l_acc[i];
        v += __shfl_xor(v, 1);
        v += __shfl_xor(v, 2);
        v += __shfl_xor(v, 4);
        v += __shfl_xor(v, 8);
        l_acc[i] = v;
    }

    for (int i = 0; i < 4; ++i) {
        float inv = 1.0f / l_acc[i];
        int qg2 = q0 + wq * 16 + l4 * 4 + i;
        float* op = out + ((size_t)(b * S_LEN + qg2)) * DHEAD + l15;
        for (int t = 0; t < 4; ++t)
            op[t * 16] = acc[t][i] * inv;
    }
}

extern "C" void kernel_launch(void* const* d_in, const int* in_sizes, int n_in,
                              void* d_out, int out_size, void* d_ws, size_t ws_size,
                              hipStream_t stream) {
    const float* Q = (const float*)d_in[0];
    const float* K = (const float*)d_in[1];
    const float* V = (const float*)d_in[2];
    const int* mask = (const int*)d_in[3];
    float* out = (float*)d_out;
    int Bn = in_sizes[0] / (S_LEN * DHEAD);

    size_t oN = (size_t)NS * Bn * S_LEN * 64;          // O_part ushorts
    size_t lN = (size_t)NS * Bn * S_LEN;               // l_part floats
    size_t bN = (size_t)Bn * 64 * 4096;                // blob ushorts (each)
    size_t need = oN * 2 + lN * 4 + bN * 2 * 2;
    if (ws_size >= need) {
        unsigned short* O_part = (unsigned short*)d_ws;
        float* l_part = (float*)(O_part + oN);
        unsigned short* Kb = (unsigned short*)(l_part + lN);
        unsigned short* Vb = Kb + bN;
        prep<<<dim3(Bn * 64), dim3(256), 0, stream>>>(K, V, Kb, Vb);
        attn_part<<<dim3(Bn * 64 * NS), dim3(256), 0, stream>>>(
            Q, Kb, Vb, mask, O_part, l_part, Bn);
        attn_reduce<<<dim3(Bn * S_LEN / 4), dim3(256), 0, stream>>>(
            O_part, l_part, out, Bn);
    } else {
        attn_fwd<<<dim3(Bn * 64), dim3(256), 0, stream>>>(Q, K, V, mask, out);
    }
}

// Round 13
// 50.830 us; speedup vs baseline: 1.7521x; 1.1147x over previous
//
#include <hip/hip_runtime.h>
#include <hip/hip_bf16.h>

#define S_LEN 4096
#define DHEAD 64
#define KBLK 64
#define CSZ 8          // k-tiles per chunk (512 kv positions)
#define NS 8           // max chunks per q-tile
#define FM 12.0f       // fixed softmax base (log2 domain); cancels in final divide

typedef __attribute__((ext_vector_type(8))) short bf16x8;
typedef __attribute__((ext_vector_type(8))) unsigned short u16x8;
typedef __attribute__((ext_vector_type(4))) float f32x4;

__device__ __forceinline__ unsigned short f2bf(float f) {
    union { float f; unsigned u; } v; v.f = f;
    unsigned r = v.u + 0x7fffu + ((v.u >> 16) & 1u);   // RNE
    return (unsigned short)(r >> 16);
}

__device__ __forceinline__ float bf2f(unsigned short h) {
    union { unsigned u; float f; } v; v.u = ((unsigned)h) << 16; return v.f;
}

__device__ __forceinline__ unsigned pack_bf2(float a, float b) {
    __hip_bfloat162 h = __float22bfloat162_rn(float2{a, b});
    union { __hip_bfloat162 h; unsigned u; } cv; cv.h = h;
    return cv.u;
}

// raw 2^x — v_exp_f32 (ISA §3). s_nop covers the TRANS-use hazard since the
// compiler's hazard recognizer may not scan inline asm. -inf -> 0 natively.
__device__ __forceinline__ float exp2_raw(float x) {
    float r;
    asm volatile("v_exp_f32 %0, %1\n\ts_nop 0" : "=v"(r) : "v"(x));
    return r;
}

// async global->LDS, 16B per lane; lds ptr is WAVE-UNIFORM base (HW adds lane*16)
__device__ __forceinline__ void gl_lds16(const void* g, void* l) {
    __builtin_amdgcn_global_load_lds(
        (const __attribute__((address_space(1))) void*)g,
        (__attribute__((address_space(3))) void*)l, 16, 0, 0);
}

// ---------------------------------------------------------------------------
// Prepass: build bf16 tile blobs = exact LDS images (swizzle + sigma baked in).
// K image byte: (kr*128 + d*2) ^ ((kr&7)<<4)
// V image byte: (d*128 + sig(k)*2) ^ (((d>>1)&7)<<4),
//   sig(k) = (ct&1)*32 + l4k*8 + (ct>>1)*4 + i  for k = ct*16 + l4k*4 + i
// ---------------------------------------------------------------------------
__global__ __launch_bounds__(256) void prep(
        const float* __restrict__ K, const float* __restrict__ V,
        unsigned short* __restrict__ Kb, unsigned short* __restrict__ Vb)
{
    const int tile = blockIdx.x;            // b*64 + kt
    const int b = tile >> 6, kt = tile & 63;
    const float* kp = K + ((size_t)(b * S_LEN + kt * KBLK)) * DHEAD;
    const float* vp = V + ((size_t)(b * S_LEN + kt * KBLK)) * DHEAD;
    unsigned short* kb = Kb + (size_t)tile * 4096;
    unsigned short* vb = Vb + (size_t)tile * 4096;
    const int tid = threadIdx.x;

    #pragma unroll
    for (int r = 0; r < 2; ++r) {
        int ci = r * 256 + tid;
        int base = ci * 16;                  // output byte
        int kr = base >> 7;
        int low = (base & 127) ^ ((kr & 7) << 4);
        int d0 = low >> 1;                   // 8 consecutive d
        u16x8 o;
        #pragma unroll
        for (int j = 0; j < 8; ++j) o[j] = f2bf(kp[kr * DHEAD + d0 + j]);
        *(u16x8*)(kb + ci * 8) = o;
    }
    #pragma unroll
    for (int r = 0; r < 2; ++r) {
        int ci = r * 256 + tid;
        int base = ci * 16;
        int d = base >> 7;
        int low = (base & 127) ^ (((d >> 1) & 7) << 4);
        int slot0 = low >> 1;                // multiple of 8
        u16x8 o;
        #pragma unroll
        for (int j = 0; j < 8; ++j) {
            int slot = slot0 + j;
            int ct = 2 * ((slot >> 2) & 1) + ((slot >> 5) & 1);
            int k = ct * 16 + ((slot >> 3) & 3) * 4 + (slot & 3);
            o[j] = f2bf(vp[k * DHEAD + d]);
        }
        *(u16x8*)(vb + ci * 8) = o;
    }
}

// ---------------------------------------------------------------------------
// Phase 1: swapped QK^T, in-register P, sigma-permuted V, blob staging via
// global_load_lds. Dbuf, 1 barrier/step. O partials bf16. Raw v_exp_f32.
// ---------------------------------------------------------------------------
__global__ __launch_bounds__(256) void attn_part(
        const float* __restrict__ Q, const unsigned short* __restrict__ Kb,
        const unsigned short* __restrict__ Vb, const int* __restrict__ mask,
        unsigned short* __restrict__ O_part, float* __restrict__ l_part, int Bn)
{
    __shared__ __align__(16) unsigned short K_lds[2][4096];
    __shared__ __align__(16) unsigned short V_lds[2][4096];
    __shared__ __align__(16) float mb[2][KBLK];

    const int blk = blockIdx.x;
    const int c   = blk & (NS - 1);
    const int bq  = 63 - ((blk >> 3) & 63);   // LPT
    const int b   = blk >> 9;
    const int nt  = bq + 1;
    const int k0  = c * CSZ;
    if (k0 >= nt) return;
    const int k1  = (k0 + CSZ < nt) ? (k0 + CSZ) : nt;

    const int tid = threadIdx.x;
    const int lane = tid & 63;
    const int wq = tid >> 6;
    const int l15 = lane & 15;
    const int l4 = lane >> 4;
    const int q0 = bq * 64;
    const int qg = q0 + wq * 16 + l15;

    const float sc = 0.125f * 1.44269504088896340736f;

    bf16x8 qf[2];
    {
        const float* qp = Q + ((size_t)(b * S_LEN + qg)) * DHEAD + l4 * 8;
        for (int kk = 0; kk < 2; ++kk) {
            float4 a = *(const float4*)(qp + kk * 32);
            float4 cq = *(const float4*)(qp + kk * 32 + 4);
            bf16x8 f;
            f[0] = (short)f2bf(a.x * sc); f[1] = (short)f2bf(a.y * sc);
            f[2] = (short)f2bf(a.z * sc); f[3] = (short)f2bf(a.w * sc);
            f[4] = (short)f2bf(cq.x * sc); f[5] = (short)f2bf(cq.y * sc);
            f[6] = (short)f2bf(cq.z * sc); f[7] = (short)f2bf(cq.w * sc);
            qf[kk] = f;
        }
    }

    int mreg;
    auto STAGE = [&](int kt, int buf) {
        const unsigned short* kb = Kb + ((size_t)(b * 64 + kt)) * 4096;
        const unsigned short* vb = Vb + ((size_t)(b * 64 + kt)) * 4096;
        #pragma unroll
        for (int r = 0; r < 2; ++r) {
            int ci = r * 256 + tid;
            int ub = (r * 256 + wq * 64) * 16;   // wave-uniform LDS byte base
            gl_lds16(kb + ci * 8, (char*)&K_lds[buf][0] + ub);
            gl_lds16(vb + ci * 8, (char*)&V_lds[buf][0] + ub);
        }
        mreg = mask[(size_t)b * S_LEN + kt * KBLK + lane];
    };

    f32x4 acc[4];
    for (int t = 0; t < 4; ++t) acc[t] = (f32x4){0.f, 0.f, 0.f, 0.f};
    f32x4 lacc = (f32x4){0.f, 0.f, 0.f, 0.f};

    STAGE(k0, 0);
    if (tid < KBLK) mb[0][tid] = mreg ? -FM : -INFINITY;
    __syncthreads();                       // drains gload_lds (vmcnt) + publishes
    int cur = 0;

    for (int kt = k0; kt < k1; ++kt) {
        const bool more = (kt + 1 < k1);
        if (more) STAGE(kt + 1, cur ^ 1);  // DMA flies under compute below

        // ---- QK^T swapped ----
        f32x4 s[4];
        __builtin_amdgcn_s_setprio(1);
        #pragma unroll
        for (int ct = 0; ct < 4; ++ct) {
            f32x4 z = (f32x4){0.f, 0.f, 0.f, 0.f};
            #pragma unroll
            for (int kk = 0; kk < 2; ++kk) {
                int row = ct * 16 + l15;
                int byte = (row * 128 + (l4 * 8 + kk * 32) * 2) ^ ((row & 7) << 4);
                bf16x8 kf = *(const bf16x8*)((const char*)&K_lds[cur][0] + byte);
                z = __builtin_amdgcn_mfma_f32_16x16x32_bf16(kf, qf[kk], z, 0, 0, 0);
            }
            s[ct] = z;
        }
        __builtin_amdgcn_s_setprio(0);

        // ---- bias + causal + raw exp2 in-register ----
        const bool diag = (kt == nt - 1);
        f32x4 p[4];
        #pragma unroll
        for (int ct = 0; ct < 4; ++ct) {
            f32x4 bias4 = *(const f32x4*)&mb[cur][ct * 16 + l4 * 4];
            f32x4 v = s[ct] + bias4;
            if (diag) {
                int kb_ = kt * 64 + ct * 16 + l4 * 4;
                #pragma unroll
                for (int i = 0; i < 4; ++i)
                    if (kb_ + i > qg) v[i] = -INFINITY;
            }
            f32x4 pe;
            pe[0] = exp2_raw(v[0]); pe[1] = exp2_raw(v[1]);
            pe[2] = exp2_raw(v[2]); pe[3] = exp2_raw(v[3]);
            p[ct] = pe;
            lacc += pe;
        }

        // ---- pack P fragments (matches sigma-permuted V) ----
        bf16x8 pf[2];
        #pragma unroll
        for (int kk = 0; kk < 2; ++kk) {
            union { unsigned u[4]; bf16x8 v; } pk;
            pk.u[0] = pack_bf2(p[kk][0], p[kk][1]);
            pk.u[1] = pack_bf2(p[kk][2], p[kk][3]);
            pk.u[2] = pack_bf2(p[kk + 2][0], p[kk + 2][1]);
            pk.u[3] = pack_bf2(p[kk + 2][2], p[kk + 2][3]);
            pf[kk] = pk.v;
        }

        // ---- PV ----
        __builtin_amdgcn_s_setprio(1);
        #pragma unroll
        for (int kk = 0; kk < 2; ++kk) {
            #pragma unroll
            for (int t = 0; t < 4; ++t) {
                int d = t * 16 + l15;
                int vbyte = (d * 128 + (l4 * 8 + kk * 32) * 2) ^ (((d >> 1) & 7) << 4);
                bf16x8 vf = *(const bf16x8*)((const char*)&V_lds[cur][0] + vbyte);
                acc[t] = __builtin_amdgcn_mfma_f32_16x16x32_bf16(pf[kk], vf, acc[t], 0, 0, 0);
            }
        }
        __builtin_amdgcn_s_setprio(0);

        if (more && tid < KBLK) mb[cur ^ 1][tid] = mreg ? -FM : -INFINITY;
        __syncthreads();                   // drains next-tile DMA + publishes
        cur ^= 1;
    }

    // ---- row denominator ----
    float la = lacc[0] + lacc[1] + lacc[2] + lacc[3];
    la += __shfl_xor(la, 16);
    la += __shfl_xor(la, 32);

    for (int i = 0; i < 4; ++i) {
        int qr = q0 + wq * 16 + l4 * 4 + i;
        size_t rb = ((size_t)c * Bn + b) * S_LEN + qr;
        unsigned short* op = O_part + rb * 64 + l15;
        #pragma unroll
        for (int t = 0; t < 4; ++t)
            op[t * 16] = f2bf(acc[t][i]);
    }
    if (l4 == 0) {
        size_t rb = ((size_t)c * Bn + b) * S_LEN + qg;
        l_part[rb] = la;
    }
}

// ---------------------------------------------------------------------------
// Phase 2: out = (sum_c O_c) / (sum_c l_c)   (bf16 partials)
// ---------------------------------------------------------------------------
__global__ __launch_bounds__(256) void attn_reduce(
        const unsigned short* __restrict__ O_part, const float* __restrict__ l_part,
        float* __restrict__ out, int Bn)
{
    int g = blockIdx.x * 4 + (threadIdx.x >> 6);
    int d = threadIdx.x & 63;
    int b = g >> 12;
    int q = g & (S_LEN - 1);
    int nc = (q >> 9) + 1;

    float den = 0.f, acc = 0.f;
    for (int cc = 0; cc < nc; ++cc) {
        size_t rb = ((size_t)cc * Bn + b) * S_LEN + q;
        den += l_part[rb];
        acc += bf2f(O_part[rb * 64 + d]);
    }
    out[((size_t)b * S_LEN + q) * 64 + d] = acc / den;
}

// ---------------------------------------------------------------------------
// Fallback: proven single-pass kernel (only if ws_size is insufficient)
// ---------------------------------------------------------------------------
__global__ __launch_bounds__(256) void attn_fwd(
        const float* __restrict__ Q, const float* __restrict__ K,
        const float* __restrict__ V, const int* __restrict__ mask,
        float* __restrict__ out)
{
    __shared__ __align__(16) unsigned short K_lds[KBLK * DHEAD];
    __shared__ __align__(16) unsigned short Vt_lds[DHEAD * KBLK];
    __shared__ __align__(16) unsigned short P_lds[4 * 16 * KBLK];
    __shared__ float mb[KBLK];

    const int tid = threadIdx.x;
    const int lane = tid & 63;
    const int wq = tid >> 6;
    const int l15 = lane & 15;
    const int l4 = lane >> 4;

    const int bq = blockIdx.x & 63;
    const int b  = blockIdx.x >> 6;
    const int q0 = bq * 64;
    const int nt = bq + 1;

    const float sc = 0.125f * 1.44269504088896340736f;

    bf16x8 qf[2];
    {
        const float* qp = Q + ((size_t)(b * S_LEN + q0 + wq * 16 + l15)) * DHEAD + l4 * 8;
        for (int kk = 0; kk < 2; ++kk) {
            float4 a = *(const float4*)(qp + kk * 32);
            float4 c = *(const float4*)(qp + kk * 32 + 4);
            bf16x8 f;
            f[0] = (short)f2bf(a.x * sc); f[1] = (short)f2bf(a.y * sc);
            f[2] = (short)f2bf(a.z * sc); f[3] = (short)f2bf(a.w * sc);
            f[4] = (short)f2bf(c.x * sc); f[5] = (short)f2bf(c.y * sc);
            f[6] = (short)f2bf(c.z * sc); f[7] = (short)f2bf(c.w * sc);
            qf[kk] = f;
        }
    }

    float4 kv[4];
    float4 vv[4];
    int    mreg;
    const int rp_  = (tid >> 4) << 1;
    const int d4v_ = (tid & 15) << 2;

    auto LOAD_TILE = [&](int kt) {
        const float* kp = K + ((size_t)(b * S_LEN + kt * KBLK)) * DHEAD;
        #pragma unroll
        for (int r = 0; r < 4; ++r) {
            int qi = tid + 256 * r;
            int kr = qi >> 4, d4 = (qi & 15) << 2;
            kv[r] = *(const float4*)(kp + kr * DHEAD + d4);
        }
        const float* vp = V + ((size_t)(b * S_LEN + kt * KBLK)) * DHEAD;
        #pragma unroll
        for (int r = 0; r < 2; ++r) {
            int row0 = rp_ + r * 32;
            vv[2 * r]     = *(const float4*)(vp + row0 * DHEAD + d4v_);
            vv[2 * r + 1] = *(const float4*)(vp + (row0 + 1) * DHEAD + d4v_);
        }
        mreg = mask[(size_t)b * S_LEN + kt * KBLK + (tid & 63)];
    };

    auto WRITE_TILE = [&]() {
        #pragma unroll
        for (int r = 0; r < 4; ++r) {
            int qi = tid + 256 * r;
            int kr = qi >> 4, d4 = (qi & 15) << 2;
            float4 v = kv[r];
            uint2 h;
            h.x = pack_bf2(v.x, v.y);
            h.y = pack_bf2(v.z, v.w);
            int byte = (kr * 128 + d4 * 2) ^ ((kr & 7) << 4);
            *(uint2*)((char*)K_lds + byte) = h;
        }
        #pragma unroll
        for (int r = 0; r < 2; ++r) {
            int row0 = rp_ + r * 32;
            float4 a = vv[2 * r];
            float4 c = vv[2 * r + 1];
            #pragma unroll
            for (int j = 0; j < 4; ++j) {
                int d = d4v_ + j;
                float aj = (j == 0) ? a.x : (j == 1) ? a.y : (j == 2) ? a.z : a.w;
                float cj = (j == 0) ? c.x : (j == 1) ? c.y : (j == 2) ? c.z : c.w;
                unsigned pack = pack_bf2(aj, cj);
                int byte = (d * 128 + row0 * 2) ^ ((d & 7) << 4);
                *(unsigned*)((char*)Vt_lds + byte) = pack;
            }
        }
        if (tid < KBLK)
            mb[tid] = mreg ? -FM : -INFINITY;
    };

    f32x4 acc[4];
    for (int t = 0; t < 4; ++t) acc[t] = (f32x4){0.f, 0.f, 0.f, 0.f};
    float l_acc[4] = {0.f, 0.f, 0.f, 0.f};

    LOAD_TILE(0);

    for (int kt = 0; kt < nt; ++kt) {
        __syncthreads();
        WRITE_TILE();
        __syncthreads();
        if (kt + 1 < nt) LOAD_TILE(kt + 1);

        f32x4 s[4];
        for (int ct = 0; ct < 4; ++ct) {
            f32x4 z = (f32x4){0.f, 0.f, 0.f, 0.f};
            for (int kk = 0; kk < 2; ++kk) {
                int row = ct * 16 + l15;
                int byte = (row * 128 + (l4 * 8 + kk * 32) * 2) ^ ((row & 7) << 4);
                bf16x8 kf = *(const bf16x8*)((const char*)K_lds + byte);
                z = __builtin_amdgcn_mfma_f32_16x16x32_bf16(qf[kk], kf, z, 0, 0, 0);
            }
            s[ct] = z;
        }

        const bool diag = (kt == nt - 1);
        for (int ct = 0; ct < 4; ++ct) {
            float bias = mb[ct * 16 + l15];
            int colg = kt * KBLK + ct * 16 + l15;
            for (int i = 0; i < 4; ++i) {
                float v = s[ct][i] + bias;
                if (diag) {
                    int qg2 = q0 + wq * 16 + l4 * 4 + i;
                    if (colg > qg2) v = -INFINITY;
                }
                float p = exp2_raw(v);
                l_acc[i] += p;
                int row = l4 * 4 + i;
                int col = ct * 16 + l15;
                int byte = (row * 128 + col * 2) ^ ((row & 7) << 4);
                *(unsigned short*)((char*)P_lds + wq * 2048 + byte) = f2bf(p);
            }
        }

        for (int kk = 0; kk < 2; ++kk) {
            int pbyte = (l15 * 128 + (l4 * 8 + kk * 32) * 2) ^ ((l15 & 7) << 4);
            bf16x8 pf = *(const bf16x8*)((const char*)P_lds + wq * 2048 + pbyte);
            for (int t = 0; t < 4; ++t) {
                int d = t * 16 + l15;
                int vbyte = (d * 128 + (l4 * 8 + kk * 32) * 2) ^ ((d & 7) << 4);
                bf16x8 vf = *(const bf16x8*)((const char*)Vt_lds + vbyte);
                acc[t] = __builtin_amdgcn_mfma_f32_16x16x32_bf16(pf, vf, acc[t], 0, 0, 0);
            }
        }
    }

    for (int i = 0; i < 4; ++i) {
        float v = l_acc[i];
        v += __shfl_xor(v, 1);
        v += __shfl_xor(v, 2);
        v += __shfl_xor(v, 4);
        v += __shfl_xor(v, 8);
        l_acc[i] = v;
    }

    for (int i = 0; i < 4; ++i) {
        float inv = 1.0f / l_acc[i];
        int qg2 = q0 + wq * 16 + l4 * 4 + i;
        float* op = out + ((size_t)(b * S_LEN + qg2)) * DHEAD + l15;
        for (int t = 0; t < 4; ++t)
            op[t * 16] = acc[t][i] * inv;
    }
}

extern "C" void kernel_launch(void* const* d_in, const int* in_sizes, int n_in,
                              void* d_out, int out_size, void* d_ws, size_t ws_size,
                              hipStream_t stream) {
    const float* Q = (const float*)d_in[0];
    const float* K = (const float*)d_in[1];
    const float* V = (const float*)d_in[2];
    const int* mask = (const int*)d_in[3];
    float* out = (float*)d_out;
    int Bn = in_sizes[0] / (S_LEN * DHEAD);

    size_t oN = (size_t)NS * Bn * S_LEN * 64;          // O_part ushorts
    size_t lN = (size_t)NS * Bn * S_LEN;               // l_part floats
    size_t bN = (size_t)Bn * 64 * 4096;                // blob ushorts (each)
    size_t need = oN * 2 + lN * 4 + bN * 2 * 2;
    if (ws_size >= need) {
        unsigned short* O_part = (unsigned short*)d_ws;
        float* l_part = (float*)(O_part + oN);
        unsigned short* Kb = (unsigned short*)(l_part + lN);
        unsigned short* Vb = Kb + bN;
        prep<<<dim3(Bn * 64), dim3(256), 0, stream>>>(K, V, Kb, Vb);
        attn_part<<<dim3(Bn * 64 * NS), dim3(256), 0, stream>>>(
            Q, Kb, Vb, mask, O_part, l_part, Bn);
        attn_reduce<<<dim3(Bn * S_LEN / 4), dim3(256), 0, stream>>>(
            O_part, l_part, out, Bn);
    } else {
        attn_fwd<<<dim3(Bn * 64), dim3(256), 0, stream>>>(Q, K, V, mask, out);
    }
}